// Round 15
// baseline (1880.484 us; speedup 1.0000x reference)
//
#include <hip/hip_runtime.h>

typedef unsigned short u16;
typedef __attribute__((ext_vector_type(4))) float f32x4;
typedef __attribute__((ext_vector_type(8))) short bf8;  // 8 bf16 in 4 VGPRs

#define MFMA16(a, b, c) __builtin_amdgcn_mfma_f32_16x16x32_bf16((a), (b), (c), 0, 0, 0)

__device__ __forceinline__ u16 f2bf(float f) {
  unsigned u = __builtin_bit_cast(unsigned, f);
  u += 0x7FFFu + ((u >> 16) & 1u);   // RNE
  return (u16)(u >> 16);
}
__device__ __forceinline__ float bf2f(u16 h) {
  unsigned u = ((unsigned)h) << 16;
  return __builtin_bit_cast(float, u);
}
__device__ __forceinline__ float sigm(float x) { return 1.0f / (1.0f + __expf(-x)); }
__device__ __forceinline__ float tanh_f(float x) {
  x = fminf(fmaxf(x, -15.f), 15.f);
  float e = __expf(2.f * x);
  return (e - 1.f) / (e + 1.f);
}

__global__ void k_fill(float* __restrict__ p, int n, float v) {
  int i = blockIdx.x * blockDim.x + threadIdx.x;
  if (i < n) p[i] = v;
}

// ------------- gate-input GEMM body (f32 in, in-kernel cast, cached stores) ----
__device__ __forceinline__ void gemm_body(
    const int* __restrict__ idx, const float* __restrict__ emb,
    const float* __restrict__ Wih, u16* __restrict__ Gpre,
    int m_base, int m0, int n0, char* smem, int tid) {
  u16 (*lA)[72] = (u16(*)[72])smem;
  u16 (*lB)[72] = (u16(*)[72])(smem + 18432);
  int lane = tid & 63, wid = tid >> 6;
  int wm = (wid >> 1) << 6, wn = (wid & 1) << 6;
  int lq = lane >> 4, lc = lane & 15;
  f32x4 acc[4][4] = {};
  for (int k0 = 0; k0 < 512; k0 += 64) {
#pragma unroll
    for (int s = 0; s < 2; s++) {
      int slot = tid + s * 256;
      int row = slot >> 2, seg = (slot & 3) << 4;
      const float* pa = emb + (size_t)idx[m_base + m0 + row] * 512 + k0 + seg;
      const float* pb = Wih + (size_t)(n0 + row) * 512 + k0 + seg;
      float4 a0 = ((const float4*)pa)[0], a1 = ((const float4*)pa)[1];
      float4 a2 = ((const float4*)pa)[2], a3 = ((const float4*)pa)[3];
      float4 b0 = ((const float4*)pb)[0], b1 = ((const float4*)pb)[1];
      float4 b2 = ((const float4*)pb)[2], b3 = ((const float4*)pb)[3];
      union { u16 h[8]; int4 v; } pk;
      pk.h[0]=f2bf(a0.x); pk.h[1]=f2bf(a0.y); pk.h[2]=f2bf(a0.z); pk.h[3]=f2bf(a0.w);
      pk.h[4]=f2bf(a1.x); pk.h[5]=f2bf(a1.y); pk.h[6]=f2bf(a1.z); pk.h[7]=f2bf(a1.w);
      *(int4*)&lA[row][seg] = pk.v;
      pk.h[0]=f2bf(a2.x); pk.h[1]=f2bf(a2.y); pk.h[2]=f2bf(a2.z); pk.h[3]=f2bf(a2.w);
      pk.h[4]=f2bf(a3.x); pk.h[5]=f2bf(a3.y); pk.h[6]=f2bf(a3.z); pk.h[7]=f2bf(a3.w);
      *(int4*)&lA[row][seg + 8] = pk.v;
      pk.h[0]=f2bf(b0.x); pk.h[1]=f2bf(b0.y); pk.h[2]=f2bf(b0.z); pk.h[3]=f2bf(b0.w);
      pk.h[4]=f2bf(b1.x); pk.h[5]=f2bf(b1.y); pk.h[6]=f2bf(b1.z); pk.h[7]=f2bf(b1.w);
      *(int4*)&lB[row][seg] = pk.v;
      pk.h[0]=f2bf(b2.x); pk.h[1]=f2bf(b2.y); pk.h[2]=f2bf(b2.z); pk.h[3]=f2bf(b2.w);
      pk.h[4]=f2bf(b3.x); pk.h[5]=f2bf(b3.y); pk.h[6]=f2bf(b3.z); pk.h[7]=f2bf(b3.w);
      *(int4*)&lB[row][seg + 8] = pk.v;
    }
    __syncthreads();
#pragma unroll
    for (int kk = 0; kk < 64; kk += 32) {
      int ko = kk + (lq << 3);
      bf8 af[4], bg[4];
#pragma unroll
      for (int i = 0; i < 4; i++) af[i] = *(const bf8*)&lA[wm + i * 16 + lc][ko];
#pragma unroll
      for (int j = 0; j < 4; j++) bg[j] = *(const bf8*)&lB[wn + j * 16 + lc][ko];
#pragma unroll
      for (int i = 0; i < 4; i++)
#pragma unroll
        for (int j = 0; j < 4; j++) acc[i][j] = MFMA16(af[i], bg[j], acc[i][j]);
    }
    __syncthreads();
  }
  int cr = lq << 2;
#pragma unroll
  for (int i = 0; i < 4; i++)
#pragma unroll
    for (int j = 0; j < 4; j++)
#pragma unroll
      for (int r = 0; r < 4; r++) {
        int m = m0 + wm + i * 16 + cr + r;
        int nn = n0 + wn + j * 16 + lc;
        Gpre[(size_t)m * 2048 + nn] = f2bf(acc[i][j][r]);
      }
}

// ------------- merged prep + chunk-0 gate GEMMs -------------
// [0,2) flg | [2,514) hrm zero | [514,2562) Whh casts | [2562,5634) tqkv |
// [5634,5650) bsum | [5650, 5650+32*Tc0) chunk-0 gemms
__global__ __launch_bounds__(256, 2) void k_prep(
    unsigned* __restrict__ flg, float* __restrict__ hrm,
    const float* __restrict__ Whh_l, u16* __restrict__ Whl,
    const float* __restrict__ Whh_r, u16* __restrict__ Whr,
    const float* __restrict__ Wq, u16* __restrict__ WqT,
    const float* __restrict__ Wk, u16* __restrict__ WkT,
    const float* __restrict__ Wv, u16* __restrict__ WvT,
    const float* __restrict__ bih_l, const float* __restrict__ bhh_l, float* __restrict__ bsl,
    const float* __restrict__ bih_r, const float* __restrict__ bhh_r, float* __restrict__ bsr,
    const int* __restrict__ seq_l, const int* __restrict__ seq_r,
    const float* __restrict__ emb_l, const float* __restrict__ emb_r,
    const float* __restrict__ Wih_l, const float* __restrict__ Wih_r,
    u16* __restrict__ Gl0, u16* __restrict__ Gr0, int Tc0) {
  __shared__ __align__(16) char smem[36864];
  int bid = blockIdx.x, tid = threadIdx.x;
  if (bid < 2) {
    flg[bid * 256 + tid] = 0u;
  } else if (bid < 514) {
    hrm[(bid - 2) * 256 + tid] = 0.f;
  } else if (bid < 2562) {                 // Whh casts: 2 x 1024 blocks
    int rel = bid - 514;
    int enc = rel >> 10;
    int i = (rel & 1023) * 256 + tid;
    const float* in = enc ? Whh_r : Whh_l;
    u16* outp = enc ? Whr : Whl;
    float4 v = ((const float4*)in)[i];
    union { u16 h[4]; uint2 u; } p;
    p.h[0] = f2bf(v.x); p.h[1] = f2bf(v.y); p.h[2] = f2bf(v.z); p.h[3] = f2bf(v.w);
    ((uint2*)outp)[i] = p.u;
  } else if (bid < 5634) {                 // tqkv: 3 x 1024 blocks
    int rel = bid - 2562;
    int which = rel >> 10;
    int g = (rel & 1023) * 256 + tid;
    const float* W = which == 0 ? Wq : (which == 1 ? Wk : Wv);
    u16* WT = which == 0 ? WqT : (which == 1 ? WkT : WvT);
    int n = g >> 15, d = (g >> 9) & 63, h = g & 511;
    WT[g] = f2bf(W[(n << 15) + (h << 6) + d]);
  } else if (bid < 5650) {                 // bsum: 2 x 8 blocks
    int rel = bid - 5634;
    int enc = rel >> 3;
    int i = (rel & 7) * 256 + tid;
    if (enc == 0) bsl[i] = bih_l[i] + bhh_l[i];
    else          bsr[i] = bih_r[i] + bhh_r[i];
  } else {                                 // chunk-0 gemms
    int rel = bid - 5650;
    int per = Tc0 << 4;
    int ge = rel >= per;
    int rem = ge ? rel - per : rel;
    gemm_body(ge ? seq_r : seq_l, ge ? emb_r : emb_l, ge ? Wih_r : Wih_l,
              ge ? Gr0 : Gl0, 0, (rem >> 4) << 7, (rem & 15) << 7, smem, tid);
  }
}

// ------------- persistent pod-parallel LSTM body (pipelined IC exchange) -------
// blocks 0..127. pod = bid&7 (enc = pod>>2, bgroup = pod&3 -> 32 b rows).
// member cg = bid>>3 owns 32 hidden channels; Whh slice in REGISTERS.
// Per-WAVE source-restricted staging: wave w polls only members 4w..4w+3 and
// loads only their columns (fast members stream in under straggler wait).
// Flags MONOTONIC in global tg. e=0: hsl history (plain cached).
// e=1: in-loop batch-mean partial atomicAdd to hrm.
__device__ void lstm_body(
    const u16* __restrict__ Gl, const u16* __restrict__ Gr,
    const u16* __restrict__ Whl, const u16* __restrict__ Whr,
    const float* __restrict__ bsl, const float* __restrict__ bsr,
    u16* __restrict__ hsl, float* __restrict__ hrm,
    unsigned* __restrict__ hx, float* __restrict__ cstate,
    unsigned* __restrict__ flg, int t0, int nT, char* hlds, int bid, int tid) {
  int pod = bid & 7, cg = bid >> 3;
  int e = pod >> 2, bg = pod & 3;
  int b0 = bg << 5, c0 = cg << 5;
  const u16* Gpre = e ? Gr : Gl;
  const u16* Whh  = e ? Whr : Whl;
  const float* bsum = e ? bsr : bsl;

  int lane = tid & 63, w = tid >> 6;
  int lq = lane >> 4, lc = lane & 15, cr = lq << 2;
  int cl = (w << 3) + (lc & 7);
  int gg0 = lc >> 3;
  int lr0 = (gg0 << 5) + cl;
  int lr1 = ((2 + gg0) << 5) + cl;
  int gc0 = (gg0 << 9) + c0 + cl;
  int gc1 = ((2 + gg0) << 9) + c0 + cl;
  float bs0 = bsum[gc0], bs1 = bsum[gc1];
  bool owner = (lc & 8) != 0;

  int gr0 = ((lr0 >> 5) << 9) + c0 + (lr0 & 31);
  int gr1 = ((lr1 >> 5) << 9) + c0 + (lr1 & 31);
  bf8 wb0[16], wb1[16];
  {
    const u16* p0 = Whh + (size_t)gr0 * 512 + (lq << 3);
    const u16* p1 = Whh + (size_t)gr1 * 512 + (lq << 3);
#pragma unroll
    for (int ks = 0; ks < 16; ks++) {
      wb0[ks] = *(const bf8*)(p0 + (ks << 5));
      wb1[ks] = *(const bf8*)(p1 + (ks << 5));
    }
  }
  float creg[2][4];
#pragma unroll
  for (int mi = 0; mi < 2; mi++)
#pragma unroll
    for (int r = 0; r < 4; r++) creg[mi][r] = 0.f;
  if (t0 > 0 && owner) {
#pragma unroll
    for (int mi = 0; mi < 2; mi++)
#pragma unroll
      for (int r = 0; r < 4; r++)
        creg[mi][r] = cstate[(size_t)((e << 7) + b0 + (mi << 4) + cr + r) * 512 + c0 + cl];
  }

  // gp prefetch for t=0 (G produced by previous dispatch)
  u16 gp[2][2][4];
#pragma unroll
  for (int mi = 0; mi < 2; mi++)
#pragma unroll
    for (int r = 0; r < 4; r++) {
      size_t rowb = (size_t)(b0 + (mi << 4) + cr + r) << 11;
      gp[mi][0][r] = Gpre[rowb + gc0];
      gp[mi][1][r] = Gpre[rowb + gc1];
    }

  int ax = (lc & 7) << 4;
  int abyte0 = lc << 10;
  int abyte1 = (16 + lc) << 10;
  int hxc = (c0 >> 1) + (w << 2) + ((lc & 7) >> 1);
  // staging remap: wave w covers u32-quad columns [16w,16w+16) = members 4w..4w+3
  const int c4 = (w << 4) + (lane >> 2);   // u32-quad column 0..63
  const int rsub = lane & 3;               // row sub-index
  const int scolb = c4 << 4;               // byte col in 1KB row
  const int srcm = (w << 2) + (lane >> 4); // source member this lane polls

  for (int t = 0; t < nT; t++) {
    int tg = t0 + t;
    f32x4 acc[2][2] = {};
    if (tg > 0) {
      // per-wave poll: only this wave's 4 source members
      {
        const unsigned* fa = flg + (pod << 6) + srcm;
        unsigned fv;
        int guard = 0;
        while (true) {
          asm volatile("global_load_dword %0, %1, off sc0 sc1"
                       : "=v"(fv) : "v"(fa) : "memory");
          asm volatile("s_waitcnt vmcnt(0)" ::: "memory");
          if (__ballot(fv >= (unsigned)tg) == ~0ull) break;
          if (++guard > 300000) break;   // degrade, never hang
        }
      }
      // stage this wave's member columns: 8 x dwordx4 per thread, single drain
      const unsigned* hxr = hx + (((size_t)((e << 1) | ((tg - 1) & 1))) << 15);
      uint4 sv[8];
#pragma unroll
      for (int i = 0; i < 8; i++) {
        int row = (i << 2) + rsub;
        const unsigned* ap = hxr + (((size_t)(b0 + row)) << 8) + (c4 << 2);
        asm volatile("global_load_dwordx4 %0, %1, off sc0 sc1"
                     : "=v"(sv[i]) : "v"(ap));
      }
      asm volatile("s_waitcnt vmcnt(0)" ::: "memory");
      __builtin_amdgcn_sched_barrier(0);
#pragma unroll
      for (int i = 0; i < 8; i++) {
        int row = (i << 2) + rsub;
        *(uint4*)(hlds + (row << 10) + (scolb ^ ((row & 7) << 4))) = sv[i];
      }
      __syncthreads();
#pragma unroll
      for (int ks = 0; ks < 16; ks++) {
        int kb = (ks << 6) + (lq << 4);
        bf8 a0 = *(const bf8*)(hlds + abyte0 + (kb ^ ax));
        bf8 a1 = *(const bf8*)(hlds + abyte1 + (kb ^ ax));
        acc[0][0] = MFMA16(a0, wb0[ks], acc[0][0]);
        acc[0][1] = MFMA16(a0, wb1[ks], acc[0][1]);
        acc[1][0] = MFMA16(a1, wb0[ks], acc[1][0]);
        acc[1][1] = MFMA16(a1, wb1[ks], acc[1][1]);
      }
      __syncthreads();   // LDS reads done before next staging
    }
    unsigned* hxw = hx + (((size_t)((e << 1) | (tg & 1))) << 15);
    float msum = 0.f;
#pragma unroll
    for (int mi = 0; mi < 2; mi++)
#pragma unroll
      for (int r = 0; r < 4; r++) {
        float v0 = acc[mi][0][r] + bf2f(gp[mi][0][r]) + bs0;
        float v1 = acc[mi][1][r] + bf2f(gp[mi][1][r]) + bs1;
        float send = sigm(v0) * tanh_f(v1);
        float recv = __shfl_xor(send, 8, 64);
        float h = 0.f;
        if (owner) {
          float c = sigm(v0) * creg[mi][r] + recv;
          creg[mi][r] = c;
          h = sigm(v1) * tanh_f(c);
          msum += h;
        }
        unsigned hb = (unsigned)f2bf(h);
        unsigned hi = __shfl_down(hb, 1, 64);
        unsigned packed = (hb & 0xffffu) | (hi << 16);
        int b = b0 + (mi << 4) + cr + r;
        if (owner && !(lane & 1)) {
          if (!e)
            *(unsigned*)(hsl + (((size_t)((tg << 7) + b)) << 9) + c0 + cl) = packed;
          unsigned* sa = hxw + (((size_t)b) << 8) + hxc;
          asm volatile("global_store_dword %0, %1, off sc0 sc1"
                       :: "v"(sa), "v"(packed) : "memory");
        }
      }
    asm volatile("s_waitcnt vmcnt(0)" ::: "memory");
    __syncthreads();
    if (tid == 0) {
      unsigned tv = (unsigned)(tg + 1);
      unsigned* fa = flg + (pod << 6) + cg;
      asm volatile("global_store_dword %0, %1, off sc0 sc1"
                   :: "v"(fa), "v"(tv) : "memory");
    }
    if (e) {  // right-encoder batch-mean partial: this block's 32 rows
      float s = msum;
      s += __shfl_xor(s, 16, 64);
      s += __shfl_xor(s, 32, 64);
      if (owner && lq == 0)
        atomicAdd(&hrm[(tg << 9) + c0 + cl], s * 0.0078125f);
    }
    if (t + 1 < nT) {
#pragma unroll
      for (int mi = 0; mi < 2; mi++)
#pragma unroll
        for (int r = 0; r < 4; r++) {
          size_t rowb = (size_t)(((t + 1) << 7) + b0 + (mi << 4) + cr + r) << 11;
          gp[mi][0][r] = Gpre[rowb + gc0];
          gp[mi][1][r] = Gpre[rowb + gc1];
        }
    }
  }
  if (owner) {
#pragma unroll
    for (int mi = 0; mi < 2; mi++)
#pragma unroll
      for (int r = 0; r < 4; r++)
        cstate[(size_t)((e << 7) + b0 + (mi << 4) + cr + r) * 512 + c0 + cl] = creg[mi][r];
  }
}

// ------------- attention body for one (head n, timestep t) ----------------------
__device__ void attn_body(
    const u16* __restrict__ hs,
    const u16* __restrict__ WqT, const u16* __restrict__ WkT, const u16* __restrict__ WvT,
    const float* __restrict__ bq, const float* __restrict__ bk, const float* __restrict__ bv,
    float* __restrict__ attmean, int n, int t, char* smem, int tid) {
  u16 (*qs)[72]  = (u16(*)[72])smem;
  u16 (*ksm)[72] = (u16(*)[72])(smem + 18432);
  u16 (*vt)[136] = (u16(*)[136])(smem + 36864);
  float (*sc)[132] = (float(*)[132])(smem + 54272);
  u16 (*ps)[136] = (u16(*)[136])smem;
  float* red = (float*)(smem + 54272);
  float* pmax = (float*)(smem + 121856);
  float* psum = (float*)(smem + 122880);

  int lane = tid & 63, wid = tid >> 6;
  int lq = lane >> 4, lc = lane & 15, cr = lq << 2;
  const u16* ol = hs + ((size_t)t << 16);

  float bqv[4], bkv[4];
#pragma unroll
  for (int nf = 0; nf < 4; nf++) {
    bqv[nf] = bq[(n << 6) + (nf << 4) + lc];
    bkv[nf] = bk[(n << 6) + (nf << 4) + lc];
  }
  float bvv[4][4];
#pragma unroll
  for (int mi = 0; mi < 4; mi++)
#pragma unroll
    for (int r = 0; r < 4; r++) bvv[mi][r] = bv[(n << 6) + (mi << 4) + cr + r];

  const u16* wq = WqT + ((size_t)n << 15);
  const u16* wk = WkT + ((size_t)n << 15);
  const u16* wv = WvT + ((size_t)n << 15);
  f32x4 aq[2][4] = {}, ak[2][4] = {}, av[4][2] = {};
  for (int ks = 0; ks < 16; ks++) {
    int ko = (ks << 5) + (lq << 3);
    bf8 a0 = *(const bf8*)&ol[(size_t)((wid << 5) + lc) * 512 + ko];
    bf8 a1 = *(const bf8*)&ol[(size_t)((wid << 5) + 16 + lc) * 512 + ko];
#pragma unroll
    for (int nf = 0; nf < 4; nf++) {
      bf8 bw = *(const bf8*)&wq[(size_t)((nf << 4) + lc) * 512 + ko];
      aq[0][nf] = MFMA16(a0, bw, aq[0][nf]);
      aq[1][nf] = MFMA16(a1, bw, aq[1][nf]);
      bf8 bw2 = *(const bf8*)&wk[(size_t)((nf << 4) + lc) * 512 + ko];
      ak[0][nf] = MFMA16(a0, bw2, ak[0][nf]);
      ak[1][nf] = MFMA16(a1, bw2, ak[1][nf]);
    }
#pragma unroll
    for (int mi = 0; mi < 4; mi++) {
      bf8 aw = *(const bf8*)&wv[(size_t)((mi << 4) + lc) * 512 + ko];
      av[mi][0] = MFMA16(aw, a0, av[mi][0]);
      av[mi][1] = MFMA16(aw, a1, av[mi][1]);
    }
  }
#pragma unroll
  for (int mi = 0; mi < 2; mi++)
#pragma unroll
    for (int nf = 0; nf < 4; nf++)
#pragma unroll
      for (int r = 0; r < 4; r++) {
        int b = (wid << 5) + (mi << 4) + cr + r;
        int d = (nf << 4) + lc;
        qs[b][d] = f2bf(aq[mi][nf][r] + bqv[nf]);
        ksm[b][d] = f2bf(ak[mi][nf][r] + bkv[nf]);
      }
#pragma unroll
  for (int mi = 0; mi < 4; mi++)
#pragma unroll
    for (int c2 = 0; c2 < 2; c2++)
#pragma unroll
      for (int r = 0; r < 4; r++) {
        int d = (mi << 4) + cr + r;
        int c = (wid << 5) + (c2 << 4) + lc;
        vt[d][c] = f2bf(av[mi][c2][r] + bvv[mi][r]);
      }
  __syncthreads();

  f32x4 as_[2][8] = {};
#pragma unroll
  for (int ks = 0; ks < 2; ks++) {
    int ko = (ks << 5) + (lq << 3);
    bf8 a0 = *(const bf8*)&qs[(wid << 5) + lc][ko];
    bf8 a1 = *(const bf8*)&qs[(wid << 5) + 16 + lc][ko];
#pragma unroll
    for (int nf = 0; nf < 8; nf++) {
      bf8 bw = *(const bf8*)&ksm[(nf << 4) + lc][ko];
      as_[0][nf] = MFMA16(a0, bw, as_[0][nf]);
      as_[1][nf] = MFMA16(a1, bw, as_[1][nf]);
    }
  }
#pragma unroll
  for (int mi = 0; mi < 2; mi++)
#pragma unroll
    for (int nf = 0; nf < 8; nf++)
#pragma unroll
      for (int r = 0; r < 4; r++)
        sc[(wid << 5) + (mi << 4) + cr + r][(nf << 4) + lc] = as_[mi][nf][r] * 0.125f;
  __syncthreads();

  {
    int row = tid & 127, half = tid >> 7;
    int cb = half << 6;
    float mx = -1e30f;
    for (int j = 0; j < 64; j++) mx = fmaxf(mx, sc[row][cb + j]);
    pmax[(half << 7) + row] = mx;
    __syncthreads();
    mx = fmaxf(pmax[row], pmax[128 + row]);
    float s = 0.f;
    for (int j = 0; j < 64; j++) { float ev = __expf(sc[row][cb + j] - mx); s += ev; sc[row][cb + j] = ev; }
    psum[(half << 7) + row] = s;
    __syncthreads();
    float inv = 1.f / (psum[row] + psum[128 + row]);
    for (int j = 0; j < 64; j++) ps[row][cb + j] = f2bf(sc[row][cb + j] * inv);
  }
  __syncthreads();

  f32x4 ao[2][4] = {};
#pragma unroll
  for (int ks = 0; ks < 4; ks++) {
    int ko = (ks << 5) + (lq << 3);
    bf8 a0 = *(const bf8*)&ps[(wid << 5) + lc][ko];
    bf8 a1 = *(const bf8*)&ps[(wid << 5) + 16 + lc][ko];
#pragma unroll
    for (int nf = 0; nf < 4; nf++) {
      bf8 bw = *(const bf8*)&vt[(nf << 4) + lc][ko];
      ao[0][nf] = MFMA16(a0, bw, ao[0][nf]);
      ao[1][nf] = MFMA16(a1, bw, ao[1][nf]);
    }
  }
  float pm[4];
#pragma unroll
  for (int nf = 0; nf < 4; nf++) {
    float s = 0.f;
#pragma unroll
    for (int mi = 0; mi < 2; mi++)
#pragma unroll
      for (int r = 0; r < 4; r++) s += ao[mi][nf][r];
    s += __shfl_xor(s, 16, 64);
    s += __shfl_xor(s, 32, 64);
    pm[nf] = s;
  }
  if (lq == 0) {
#pragma unroll
    for (int nf = 0; nf < 4; nf++) red[(wid << 6) + (nf << 4) + lc] = pm[nf];
  }
  __syncthreads();
  if (tid < 64) {
    float s = red[tid] + red[64 + tid] + red[128 + tid] + red[192 + tid];
    attmean[(t << 9) + (n << 6) + tid] = s * 0.0078125f;
  }
}

// ------- fused: [0,128) LSTM chunk c; [128,128+32*nextT) GEMM chunk c+1;
//         [128+32*nextT, +8*prevT) attn for chunk c-1 (data from prior dispatch) ----
__global__ __launch_bounds__(256, 1) void k_fused(
    const u16* __restrict__ Gl, const u16* __restrict__ Gr,
    u16* __restrict__ Ggl, u16* __restrict__ Ggr,
    const int* __restrict__ seq_l, const int* __restrict__ seq_r,
    const float* __restrict__ emb_l, const float* __restrict__ emb_r,
    const float* __restrict__ Wih_l, const float* __restrict__ Wih_r,
    const u16* __restrict__ Whl, const u16* __restrict__ Whr,
    const float* __restrict__ bsl, const float* __restrict__ bsr,
    u16* __restrict__ hsl, float* __restrict__ hrm,
    unsigned* __restrict__ hx, float* __restrict__ cstate,
    unsigned* __restrict__ flg,
    const u16* __restrict__ WqT, const u16* __restrict__ WkT, const u16* __restrict__ WvT,
    const float* __restrict__ bq, const float* __restrict__ bk, const float* __restrict__ bv,
    float* __restrict__ am,
    int t0, int nT, int gmb, int nextT, int prev_t0) {
  __shared__ __align__(16) char smem[123904];
  int bid = blockIdx.x, tid = threadIdx.x;
  if (bid < 128) {
    lstm_body(Gl, Gr, Whl, Whr, bsl, bsr, hsl, hrm, hx, cstate, flg,
              t0, nT, smem, bid, tid);
  } else {
    int gb = bid - 128;
    int gemmN = nextT << 5;
    if (gb < gemmN) {
      int per = nextT << 4;
      int ge = gb >= per;
      int rem = ge ? gb - per : gb;
      gemm_body(ge ? seq_r : seq_l, ge ? emb_r : emb_l, ge ? Wih_r : Wih_l,
                ge ? Ggr : Ggl, gmb, (rem >> 4) << 7, (rem & 15) << 7, smem, tid);
    } else {
      int ab = gb - gemmN;
      attn_body(hsl, WqT, WkT, WvT, bq, bk, bv, am, ab & 7, prev_t0 + (ab >> 3),
                smem, tid);
    }
  }
}

// ------------- standalone attn for the last chunk -------------
__global__ __launch_bounds__(256, 1) void k_attn(
    const u16* __restrict__ hs,
    const u16* __restrict__ WqT, const u16* __restrict__ WkT, const u16* __restrict__ WvT,
    const float* __restrict__ bq, const float* __restrict__ bk, const float* __restrict__ bv,
    float* __restrict__ attmean, int t0) {
  __shared__ __align__(16) char smem[123904];
  int bid = blockIdx.x;
  attn_body(hs, WqT, WkT, WvT, bq, bk, bv, attmean, bid & 7, t0 + (bid >> 3),
            smem, threadIdx.x);
}

// ------------- attmean @ Wo + bo -------------
__global__ __launch_bounds__(256) void k_olm(const float* __restrict__ am, const float* __restrict__ Wo,
                                             const float* __restrict__ bo, float* __restrict__ olm) {
  __shared__ float row[512];
  int t = blockIdx.x >> 1, h0 = (blockIdx.x & 1) << 8;
  int tid = threadIdx.x;
  row[tid] = am[(t << 9) + tid];
  row[tid + 256] = am[(t << 9) + 256 + tid];
  __syncthreads();
  int h = h0 + tid;
  float s = bo[h];
  for (int k = 0; k < 512; k++) s += row[k] * Wo[(k << 9) + h];
  olm[(t << 9) + h] = s;
}

// ------------- final MLP + softmax -------------
__global__ __launch_bounds__(64) void k_final(const float* __restrict__ olmp, const float* __restrict__ hrm,
                                              const float* __restrict__ Wh, const float* __restrict__ bh,
                                              const float* __restrict__ Wa, const float* __restrict__ ba,
                                              float* __restrict__ out) {
  __shared__ float cat[1024];
  int t = blockIdx.x, j = threadIdx.x;
  for (int i = j; i < 512; i += 64) {
    cat[i] = olmp[(t << 9) + i];
    cat[512 + i] = hrm[(t << 9) + i];
  }
  __syncthreads();
  float f = bh[j];
  for (int k = 0; k < 1024; k++) f += cat[k] * Wh[(k << 6) + j];
  float p0 = f * Wa[j * 2], p1 = f * Wa[j * 2 + 1];
#pragma unroll
  for (int o = 32; o > 0; o >>= 1) { p0 += __shfl_down(p0, o); p1 += __shfl_down(p1, o); }
  if (j == 0) {
    p0 += ba[0]; p1 += ba[1];
    float m = fmaxf(p0, p1);
    float e0 = __expf(p0 - m), e1 = __expf(p1 - m);
    float inv = 1.f / (e0 + e1);
    out[t * 2] = e0 * inv;
    out[t * 2 + 1] = e1 * inv;
  }
}

extern "C" void kernel_launch(void* const* d_in, const int* in_sizes, int n_in,
                              void* d_out, int out_size, void* d_ws, size_t ws_size,
                              hipStream_t stream) {
  const int*   seq_l = (const int*)d_in[0];
  const int*   seq_r = (const int*)d_in[1];
  const float* emb_l = (const float*)d_in[2];
  const float* emb_r = (const float*)d_in[3];
  const float* Wih_l = (const float*)d_in[4];
  const float* Whh_l = (const float*)d_in[5];
  const float* bih_l = (const float*)d_in[6];
  const float* bhh_l = (const float*)d_in[7];
  const float* Wih_r = (const float*)d_in[8];
  const float* Whh_r = (const float*)d_in[9];
  const float* bih_r = (const float*)d_in[10];
  const float* bhh_r = (const float*)d_in[11];
  const float* Wq = (const float*)d_in[12];
  const float* bq = (const float*)d_in[13];
  const float* Wk = (const float*)d_in[14];
  const float* bk = (const float*)d_in[15];
  const float* Wv = (const float*)d_in[16];
  const float* bv = (const float*)d_in[17];
  const float* Wo = (const float*)d_in[18];
  const float* bo = (const float*)d_in[19];
  const float* Wh = (const float*)d_in[20];
  const float* bhc = (const float*)d_in[21];
  const float* Wa = (const float*)d_in[22];
  const float* ba = (const float*)d_in[23];
  float* out = (float*)d_out;

  char* ws = (char*)d_ws;
  size_t off = 0;
  auto alloc = [&](size_t bytes) { char* p = ws + off; off += (bytes + 255) & ~(size_t)255; return p; };
  u16*   hsl  = (u16*)alloc(33554432);
  u16*   Whl  = (u16*)alloc(2097152);
  u16*   Whr  = (u16*)alloc(2097152);
  u16*   WqT  = (u16*)alloc(524288);
  u16*   WkT  = (u16*)alloc(524288);
  u16*   WvT  = (u16*)alloc(524288);
  float* bsl  = (float*)alloc(8192);
  float* bsr  = (float*)alloc(8192);
  unsigned* hx = (unsigned*)alloc(524288);   // 4 regions x 32768 u32
  float* cst  = (float*)alloc(524288);
  unsigned* flg = (unsigned*)alloc(2048);    // 8 pods x 64 u32
  float* am   = (float*)alloc(524288);
  float* hrm  = (float*)alloc(524288);
  float* olm  = (float*)alloc(524288);
  size_t fixed = off;

  // chunk ladder: prefer bigger chunks if workspace allows
  int chunks[4]; int nch = 0; int Tmax = 0;
  if (fixed + 4ull * 128 * 524288ull <= ws_size) {
    chunks[0] = 128; chunks[1] = 128; nch = 2; Tmax = 128;
  } else if (fixed + 4ull * 96 * 524288ull <= ws_size) {
    chunks[0] = 96; chunks[1] = 96; chunks[2] = 64; nch = 3; Tmax = 96;
  } else if (fixed + 4ull * 64 * 524288ull <= ws_size) {
    chunks[0] = chunks[1] = chunks[2] = chunks[3] = 64; nch = 4; Tmax = 64;
  } else {
    k_fill<<<2, 256, 0, stream>>>(out, out_size, 0.25f);
    return;
  }
  size_t gbytes = (size_t)Tmax * 524288ull;
  u16* Glb[2]; u16* Grb[2];
  Glb[0] = (u16*)alloc(gbytes); Glb[1] = (u16*)alloc(gbytes);
  Grb[0] = (u16*)alloc(gbytes); Grb[1] = (u16*)alloc(gbytes);

  // merged prep + chunk-0 gemms
  k_prep<<<5650 + (chunks[0] << 5), 256, 0, stream>>>(
      flg, hrm, Whh_l, Whl, Whh_r, Whr, Wq, WqT, Wk, WkT, Wv, WvT,
      bih_l, bhh_l, bsl, bih_r, bhh_r, bsr,
      seq_l, seq_r, emb_l, emb_r, Wih_l, Wih_r, Glb[0], Grb[0], chunks[0]);

  int t0 = 0;
  for (int c = 0; c < nch; c++) {
    int nT = chunks[c];
    int nextT = (c + 1 < nch) ? chunks[c + 1] : 0;
    int prevT = (c > 0) ? chunks[c - 1] : 0;
    int grid = 128 + (nextT << 5) + (prevT << 3);
    k_fused<<<grid, 256, 0, stream>>>(
        Glb[c & 1], Grb[c & 1], Glb[(c + 1) & 1], Grb[(c + 1) & 1],
        seq_l, seq_r, emb_l, emb_r, Wih_l, Wih_r,
        Whl, Whr, bsl, bsr, hsl, hrm, hx, cst, flg,
        WqT, WkT, WvT, bq, bk, bv, am,
        t0, nT, (t0 + nT) << 7, nextT, t0 - prevT);
    t0 += nT;
  }
  int lastT = chunks[nch - 1];
  k_attn<<<lastT << 3, 256, 0, stream>>>(hsl, WqT, WkT, WvT, bq, bk, bv, am,
                                         256 - lastT);
  k_olm<<<512, 256, 0, stream>>>(am, Wo, bo, olm);
  k_final<<<256, 64, 0, stream>>>(olm, hrm, Wh, bhc, Wa, ba, out);
}

// Round 17
// 1693.001 us; speedup vs baseline: 1.1107x; 1.1107x over previous
//
#include <hip/hip_runtime.h>

typedef unsigned short u16;
typedef __attribute__((ext_vector_type(4))) float f32x4;
typedef __attribute__((ext_vector_type(8))) short bf8;  // 8 bf16 in 4 VGPRs

#define MFMA16(a, b, c) __builtin_amdgcn_mfma_f32_16x16x32_bf16((a), (b), (c), 0, 0, 0)

__device__ __forceinline__ u16 f2bf(float f) {
  unsigned u = __builtin_bit_cast(unsigned, f);
  u += 0x7FFFu + ((u >> 16) & 1u);   // RNE
  return (u16)(u >> 16);
}
__device__ __forceinline__ float bf2f(u16 h) {
  unsigned u = ((unsigned)h) << 16;
  return __builtin_bit_cast(float, u);
}
__device__ __forceinline__ float sigm(float x) { return 1.0f / (1.0f + __expf(-x)); }
__device__ __forceinline__ float tanh_f(float x) {
  x = fminf(fmaxf(x, -15.f), 15.f);
  float e = __expf(2.f * x);
  return (e - 1.f) / (e + 1.f);
}

__global__ void k_fill(float* __restrict__ p, int n, float v) {
  int i = blockIdx.x * blockDim.x + threadIdx.x;
  if (i < n) p[i] = v;
}

// ------------- gate-input GEMM body (f32 in, in-kernel cast, cached stores) ----
__device__ __forceinline__ void gemm_body(
    const int* __restrict__ idx, const float* __restrict__ emb,
    const float* __restrict__ Wih, u16* __restrict__ Gpre,
    int m_base, int m0, int n0, char* smem, int tid) {
  u16 (*lA)[72] = (u16(*)[72])smem;
  u16 (*lB)[72] = (u16(*)[72])(smem + 18432);
  int lane = tid & 63, wid = tid >> 6;
  int wm = (wid >> 1) << 6, wn = (wid & 1) << 6;
  int lq = lane >> 4, lc = lane & 15;
  f32x4 acc[4][4] = {};
  for (int k0 = 0; k0 < 512; k0 += 64) {
#pragma unroll
    for (int s = 0; s < 2; s++) {
      int slot = tid + s * 256;
      int row = slot >> 2, seg = (slot & 3) << 4;
      const float* pa = emb + (size_t)idx[m_base + m0 + row] * 512 + k0 + seg;
      const float* pb = Wih + (size_t)(n0 + row) * 512 + k0 + seg;
      float4 a0 = ((const float4*)pa)[0], a1 = ((const float4*)pa)[1];
      float4 a2 = ((const float4*)pa)[2], a3 = ((const float4*)pa)[3];
      float4 b0 = ((const float4*)pb)[0], b1 = ((const float4*)pb)[1];
      float4 b2 = ((const float4*)pb)[2], b3 = ((const float4*)pb)[3];
      union { u16 h[8]; int4 v; } pk;
      pk.h[0]=f2bf(a0.x); pk.h[1]=f2bf(a0.y); pk.h[2]=f2bf(a0.z); pk.h[3]=f2bf(a0.w);
      pk.h[4]=f2bf(a1.x); pk.h[5]=f2bf(a1.y); pk.h[6]=f2bf(a1.z); pk.h[7]=f2bf(a1.w);
      *(int4*)&lA[row][seg] = pk.v;
      pk.h[0]=f2bf(a2.x); pk.h[1]=f2bf(a2.y); pk.h[2]=f2bf(a2.z); pk.h[3]=f2bf(a2.w);
      pk.h[4]=f2bf(a3.x); pk.h[5]=f2bf(a3.y); pk.h[6]=f2bf(a3.z); pk.h[7]=f2bf(a3.w);
      *(int4*)&lA[row][seg + 8] = pk.v;
      pk.h[0]=f2bf(b0.x); pk.h[1]=f2bf(b0.y); pk.h[2]=f2bf(b0.z); pk.h[3]=f2bf(b0.w);
      pk.h[4]=f2bf(b1.x); pk.h[5]=f2bf(b1.y); pk.h[6]=f2bf(b1.z); pk.h[7]=f2bf(b1.w);
      *(int4*)&lB[row][seg] = pk.v;
      pk.h[0]=f2bf(b2.x); pk.h[1]=f2bf(b2.y); pk.h[2]=f2bf(b2.z); pk.h[3]=f2bf(b2.w);
      pk.h[4]=f2bf(b3.x); pk.h[5]=f2bf(b3.y); pk.h[6]=f2bf(b3.z); pk.h[7]=f2bf(b3.w);
      *(int4*)&lB[row][seg + 8] = pk.v;
    }
    __syncthreads();
#pragma unroll
    for (int kk = 0; kk < 64; kk += 32) {
      int ko = kk + (lq << 3);
      bf8 af[4], bg[4];
#pragma unroll
      for (int i = 0; i < 4; i++) af[i] = *(const bf8*)&lA[wm + i * 16 + lc][ko];
#pragma unroll
      for (int j = 0; j < 4; j++) bg[j] = *(const bf8*)&lB[wn + j * 16 + lc][ko];
#pragma unroll
      for (int i = 0; i < 4; i++)
#pragma unroll
        for (int j = 0; j < 4; j++) acc[i][j] = MFMA16(af[i], bg[j], acc[i][j]);
    }
    __syncthreads();
  }
  int cr = lq << 2;
#pragma unroll
  for (int i = 0; i < 4; i++)
#pragma unroll
    for (int j = 0; j < 4; j++)
#pragma unroll
      for (int r = 0; r < 4; r++) {
        int m = m0 + wm + i * 16 + cr + r;
        int nn = n0 + wn + j * 16 + lc;
        Gpre[(size_t)m * 2048 + nn] = f2bf(acc[i][j][r]);
      }
}

// ------------- merged prep + chunk-0 gate GEMMs -------------
// [0,2) flg zero | [2,2050) Whh casts | [2050,5122) tqkv | [5122,5138) bsum |
// [5138, 5138+32*Tc) chunk-0 gemms
__global__ __launch_bounds__(256, 2) void k_prep(
    unsigned* __restrict__ flg,
    const float* __restrict__ Whh_l, u16* __restrict__ Whl,
    const float* __restrict__ Whh_r, u16* __restrict__ Whr,
    const float* __restrict__ Wq, u16* __restrict__ WqT,
    const float* __restrict__ Wk, u16* __restrict__ WkT,
    const float* __restrict__ Wv, u16* __restrict__ WvT,
    const float* __restrict__ bih_l, const float* __restrict__ bhh_l, float* __restrict__ bsl,
    const float* __restrict__ bih_r, const float* __restrict__ bhh_r, float* __restrict__ bsr,
    const int* __restrict__ seq_l, const int* __restrict__ seq_r,
    const float* __restrict__ emb_l, const float* __restrict__ emb_r,
    const float* __restrict__ Wih_l, const float* __restrict__ Wih_r,
    u16* __restrict__ Gl0, u16* __restrict__ Gr0, int Tc) {
  __shared__ __align__(16) char smem[36864];
  int bid = blockIdx.x, tid = threadIdx.x;
  if (bid < 2) {
    flg[bid * 256 + tid] = 0u;
  } else if (bid < 2050) {                 // Whh casts: 2 x 1024 blocks
    int rel = bid - 2;
    int enc = rel >> 10;
    int i = (rel & 1023) * 256 + tid;
    const float* in = enc ? Whh_r : Whh_l;
    u16* outp = enc ? Whr : Whl;
    float4 v = ((const float4*)in)[i];
    union { u16 h[4]; uint2 u; } p;
    p.h[0] = f2bf(v.x); p.h[1] = f2bf(v.y); p.h[2] = f2bf(v.z); p.h[3] = f2bf(v.w);
    ((uint2*)outp)[i] = p.u;
  } else if (bid < 5122) {                 // tqkv: 3 x 1024 blocks
    int rel = bid - 2050;
    int which = rel >> 10;
    int g = (rel & 1023) * 256 + tid;
    const float* W = which == 0 ? Wq : (which == 1 ? Wk : Wv);
    u16* WT = which == 0 ? WqT : (which == 1 ? WkT : WvT);
    int n = g >> 15, d = (g >> 9) & 63, h = g & 511;
    WT[g] = f2bf(W[(n << 15) + (h << 6) + d]);
  } else if (bid < 5138) {                 // bsum: 2 x 8 blocks
    int rel = bid - 5122;
    int enc = rel >> 3;
    int i = (rel & 7) * 256 + tid;
    if (enc == 0) bsl[i] = bih_l[i] + bhh_l[i];
    else          bsr[i] = bih_r[i] + bhh_r[i];
  } else {                                 // chunk-0 gemms
    int rel = bid - 5138;
    int per = Tc << 4;
    int ge = rel >= per;
    int rem = ge ? rel - per : rel;
    gemm_body(ge ? seq_r : seq_l, ge ? emb_r : emb_l, ge ? Wih_r : Wih_l,
              ge ? Gr0 : Gl0, 0, (rem >> 4) << 7, (rem & 15) << 7, smem, tid);
  }
}

// ------------- persistent pod-parallel LSTM body (pipelined IC exchange) -------
// blocks 0..127. pod = bid&7 (enc = pod>>2, bgroup = pod&3 -> 32 b rows).
// member cg = bid>>3 owns 32 hidden channels; Whh slice in REGISTERS.
// h exchange via sc0sc1 loads/stores, pipelined. Flags MONOTONIC in global tg.
__device__ void lstm_body(
    const u16* __restrict__ Gl, const u16* __restrict__ Gr,
    const u16* __restrict__ Whl, const u16* __restrict__ Whr,
    const float* __restrict__ bsl, const float* __restrict__ bsr,
    u16* __restrict__ hsl, u16* __restrict__ hsr,
    unsigned* __restrict__ hx, float* __restrict__ cstate,
    unsigned* __restrict__ flg, int t0, int nT, char* hlds, int bid, int tid) {
  int pod = bid & 7, cg = bid >> 3;
  int e = pod >> 2, bg = pod & 3;
  int b0 = bg << 5, c0 = cg << 5;
  const u16* Gpre = e ? Gr : Gl;
  const u16* Whh  = e ? Whr : Whl;
  const float* bsum = e ? bsr : bsl;
  u16* hs = e ? hsr : hsl;

  int lane = tid & 63, w = tid >> 6;
  int lq = lane >> 4, lc = lane & 15, cr = lq << 2;
  int cl = (w << 3) + (lc & 7);
  int gg0 = lc >> 3;
  int lr0 = (gg0 << 5) + cl;
  int lr1 = ((2 + gg0) << 5) + cl;
  int gc0 = (gg0 << 9) + c0 + cl;
  int gc1 = ((2 + gg0) << 9) + c0 + cl;
  float bs0 = bsum[gc0], bs1 = bsum[gc1];
  bool owner = (lc & 8) != 0;

  int gr0 = ((lr0 >> 5) << 9) + c0 + (lr0 & 31);
  int gr1 = ((lr1 >> 5) << 9) + c0 + (lr1 & 31);
  bf8 wb0[16], wb1[16];
  {
    const u16* p0 = Whh + (size_t)gr0 * 512 + (lq << 3);
    const u16* p1 = Whh + (size_t)gr1 * 512 + (lq << 3);
#pragma unroll
    for (int ks = 0; ks < 16; ks++) {
      wb0[ks] = *(const bf8*)(p0 + (ks << 5));
      wb1[ks] = *(const bf8*)(p1 + (ks << 5));
    }
  }
  float creg[2][4];
#pragma unroll
  for (int mi = 0; mi < 2; mi++)
#pragma unroll
    for (int r = 0; r < 4; r++) creg[mi][r] = 0.f;
  if (t0 > 0 && owner) {
#pragma unroll
    for (int mi = 0; mi < 2; mi++)
#pragma unroll
      for (int r = 0; r < 4; r++)
        creg[mi][r] = cstate[(size_t)((e << 7) + b0 + (mi << 4) + cr + r) * 512 + c0 + cl];
  }

  // gp prefetch for t=0 (G produced by previous dispatch)
  u16 gp[2][2][4];
#pragma unroll
  for (int mi = 0; mi < 2; mi++)
#pragma unroll
    for (int r = 0; r < 4; r++) {
      size_t rowb = (size_t)(b0 + (mi << 4) + cr + r) << 11;
      gp[mi][0][r] = Gpre[rowb + gc0];
      gp[mi][1][r] = Gpre[rowb + gc1];
    }

  int ax = (lc & 7) << 4;
  int abyte0 = lc << 10;
  int abyte1 = (16 + lc) << 10;
  int hxc = (c0 >> 1) + (w << 2) + ((lc & 7) >> 1);
  const int srow = tid >> 6;
  const int scolb = (tid & 63) << 4;

  for (int t = 0; t < nT; t++) {
    int tg = t0 + t;
    f32x4 acc[2][2] = {};
    if (tg > 0) {
      if (t > 0) {
        // wave-parallel flag poll: lane i watches member (i&15); target = global tg
        if (tid < 64) {
          const unsigned* fa = flg + (pod << 6) + (lane & 15);
          unsigned fv;
          int guard = 0;
          while (true) {
            asm volatile("global_load_dword %0, %1, off sc0 sc1"
                         : "=v"(fv) : "v"(fa) : "memory");
            asm volatile("s_waitcnt vmcnt(0)" ::: "memory");
            if (__ballot(fv >= (unsigned)tg) == ~0ull) break;
            if (++guard > 300000) break;   // degrade, never hang
          }
        }
        __syncthreads();
      }
      // stage h(t-1): 32 rows x 1KB; 8 x dwordx4 per thread, single vmcnt drain
      const unsigned* hxr = hx + (((size_t)((e << 1) | ((tg - 1) & 1))) << 15);
      uint4 sv[8];
#pragma unroll
      for (int i = 0; i < 8; i++) {
        int row = (i << 2) + srow;
        const unsigned* ap = hxr + (((size_t)(b0 + row)) << 8) + ((tid & 63) << 2);
        asm volatile("global_load_dwordx4 %0, %1, off sc0 sc1"
                     : "=v"(sv[i]) : "v"(ap));
      }
      asm volatile("s_waitcnt vmcnt(0)" ::: "memory");
      __builtin_amdgcn_sched_barrier(0);
#pragma unroll
      for (int i = 0; i < 8; i++) {
        int row = (i << 2) + srow;
        *(uint4*)(hlds + (row << 10) + (scolb ^ ((row & 7) << 4))) = sv[i];
      }
      __syncthreads();
#pragma unroll
      for (int ks = 0; ks < 16; ks++) {
        int kb = (ks << 6) + (lq << 4);
        bf8 a0 = *(const bf8*)(hlds + abyte0 + (kb ^ ax));
        bf8 a1 = *(const bf8*)(hlds + abyte1 + (kb ^ ax));
        acc[0][0] = MFMA16(a0, wb0[ks], acc[0][0]);
        acc[0][1] = MFMA16(a0, wb1[ks], acc[0][1]);
        acc[1][0] = MFMA16(a1, wb0[ks], acc[1][0]);
        acc[1][1] = MFMA16(a1, wb1[ks], acc[1][1]);
      }
      __syncthreads();   // LDS reads done before next staging
    }
    unsigned* hxw = hx + (((size_t)((e << 1) | (tg & 1))) << 15);
#pragma unroll
    for (int mi = 0; mi < 2; mi++)
#pragma unroll
      for (int r = 0; r < 4; r++) {
        float v0 = acc[mi][0][r] + bf2f(gp[mi][0][r]) + bs0;
        float v1 = acc[mi][1][r] + bf2f(gp[mi][1][r]) + bs1;
        float send = sigm(v0) * tanh_f(v1);
        float recv = __shfl_xor(send, 8, 64);
        float h = 0.f;
        if (owner) {
          float c = sigm(v0) * creg[mi][r] + recv;
          creg[mi][r] = c;
          h = sigm(v1) * tanh_f(c);
        }
        unsigned hb = (unsigned)f2bf(h);
        unsigned hi = __shfl_down(hb, 1, 64);
        unsigned packed = (hb & 0xffffu) | (hi << 16);
        int b = b0 + (mi << 4) + cr + r;
        if (owner && !(lane & 1)) {
          *(unsigned*)(hs + (((size_t)((tg << 7) + b)) << 9) + c0 + cl) = packed;
          unsigned* sa = hxw + (((size_t)b) << 8) + hxc;
          asm volatile("global_store_dword %0, %1, off sc0 sc1"
                       :: "v"(sa), "v"(packed) : "memory");
        }
      }
    asm volatile("s_waitcnt vmcnt(0)" ::: "memory");
    __syncthreads();
    if (tid == 0) {
      unsigned tv = (unsigned)(tg + 1);
      unsigned* fa = flg + (pod << 6) + cg;
      asm volatile("global_store_dword %0, %1, off sc0 sc1"
                   :: "v"(fa), "v"(tv) : "memory");
    }
    if (t + 1 < nT) {
#pragma unroll
      for (int mi = 0; mi < 2; mi++)
#pragma unroll
        for (int r = 0; r < 4; r++) {
          size_t rowb = (size_t)(((t + 1) << 7) + b0 + (mi << 4) + cr + r) << 11;
          gp[mi][0][r] = Gpre[rowb + gc0];
          gp[mi][1][r] = Gpre[rowb + gc1];
        }
    }
  }
  if (owner) {
#pragma unroll
    for (int mi = 0; mi < 2; mi++)
#pragma unroll
      for (int r = 0; r < 4; r++)
        cstate[(size_t)((e << 7) + b0 + (mi << 4) + cr + r) * 512 + c0 + cl] = creg[mi][r];
  }
}

// ------- fused: blocks 0..127 = LSTM chunk c; blocks 128+ = GEMM chunk c+1 -------
// smem 81920 > 160KB/2 forces 1 block/CU for the lstm arm.
__global__ __launch_bounds__(256, 1) void k_fused(
    const u16* __restrict__ Gl, const u16* __restrict__ Gr,
    u16* __restrict__ Ggl, u16* __restrict__ Ggr,
    const int* __restrict__ seq_l, const int* __restrict__ seq_r,
    const float* __restrict__ emb_l, const float* __restrict__ emb_r,
    const float* __restrict__ Wih_l, const float* __restrict__ Wih_r,
    const u16* __restrict__ Whl, const u16* __restrict__ Whr,
    const float* __restrict__ bsl, const float* __restrict__ bsr,
    u16* __restrict__ hsl, u16* __restrict__ hsr,
    unsigned* __restrict__ hx, float* __restrict__ cstate,
    unsigned* __restrict__ flg, int t0, int nT, int gmb, int Tc) {
  __shared__ __align__(16) char smem[81920];
  int bid = blockIdx.x, tid = threadIdx.x;
  if (bid < 128) {
    lstm_body(Gl, Gr, Whl, Whr, bsl, bsr, hsl, hsr, hx, cstate, flg,
              t0, nT, smem, bid, tid);
  } else {
    int gb = bid - 128;
    int per = Tc << 4;
    int ge = gb >= per;
    int rem = ge ? gb - per : gb;
    gemm_body(ge ? seq_r : seq_l, ge ? emb_r : emb_l, ge ? Wih_r : Wih_l,
              ge ? Ggr : Ggl, gmb, (rem >> 4) << 7, (rem & 15) << 7, smem, tid);
  }
}

// ------------- mean over batch of right-encoder h (vectorized) -------------
__global__ __launch_bounds__(256) void k_meanr(const u16* __restrict__ hs, float* __restrict__ out) {
  __shared__ float part[4][512];
  int t = blockIdx.x, tid = threadIdx.x;
  int rg = tid >> 6, ln = tid & 63;
  float s[8] = {};
  for (int b = rg << 5; b < (rg << 5) + 32; b++) {
    bf8 v = *(const bf8*)(hs + (((size_t)((t << 7) + b)) << 9) + (ln << 3));
#pragma unroll
    for (int j = 0; j < 8; j++) s[j] += bf2f((u16)v[j]);
  }
#pragma unroll
  for (int j = 0; j < 8; j++) part[rg][(ln << 3) + j] = s[j];
  __syncthreads();
  for (int c = tid; c < 512; c += 256)
    out[(t << 9) + c] = (part[0][c] + part[1][c] + part[2][c] + part[3][c]) * 0.0078125f;
}

// ------------- fused attention per (head, t); emits pooled att mean -------------
__global__ __launch_bounds__(256, 1) void k_attn(
    const u16* __restrict__ hs,
    const u16* __restrict__ WqT, const u16* __restrict__ WkT, const u16* __restrict__ WvT,
    const float* __restrict__ bq, const float* __restrict__ bk, const float* __restrict__ bv,
    float* __restrict__ attmean) {
  __shared__ __align__(16) char smem[123904];
  u16 (*qs)[72]  = (u16(*)[72])smem;
  u16 (*ksm)[72] = (u16(*)[72])(smem + 18432);
  u16 (*vt)[136] = (u16(*)[136])(smem + 36864);
  float (*sc)[132] = (float(*)[132])(smem + 54272);
  u16 (*ps)[136] = (u16(*)[136])smem;
  float* red = (float*)(smem + 54272);
  float* pmax = (float*)(smem + 121856);
  float* psum = (float*)(smem + 122880);

  int bid = blockIdx.x;
  int n = bid >> 8, t = bid & 255;
  int tid = threadIdx.x, lane = tid & 63, wid = tid >> 6;
  int lq = lane >> 4, lc = lane & 15, cr = lq << 2;
  const u16* ol = hs + ((size_t)t << 16);

  float bqv[4], bkv[4];
#pragma unroll
  for (int nf = 0; nf < 4; nf++) {
    bqv[nf] = bq[(n << 6) + (nf << 4) + lc];
    bkv[nf] = bk[(n << 6) + (nf << 4) + lc];
  }
  float bvv[4][4];
#pragma unroll
  for (int mi = 0; mi < 4; mi++)
#pragma unroll
    for (int r = 0; r < 4; r++) bvv[mi][r] = bv[(n << 6) + (mi << 4) + cr + r];

  const u16* wq = WqT + ((size_t)n << 15);
  const u16* wk = WkT + ((size_t)n << 15);
  const u16* wv = WvT + ((size_t)n << 15);
  f32x4 aq[2][4] = {}, ak[2][4] = {}, av[4][2] = {};
  for (int ks = 0; ks < 16; ks++) {
    int ko = (ks << 5) + (lq << 3);
    bf8 a0 = *(const bf8*)&ol[(size_t)((wid << 5) + lc) * 512 + ko];
    bf8 a1 = *(const bf8*)&ol[(size_t)((wid << 5) + 16 + lc) * 512 + ko];
#pragma unroll
    for (int nf = 0; nf < 4; nf++) {
      bf8 bw = *(const bf8*)&wq[(size_t)((nf << 4) + lc) * 512 + ko];
      aq[0][nf] = MFMA16(a0, bw, aq[0][nf]);
      aq[1][nf] = MFMA16(a1, bw, aq[1][nf]);
      bf8 bw2 = *(const bf8*)&wk[(size_t)((nf << 4) + lc) * 512 + ko];
      ak[0][nf] = MFMA16(a0, bw2, ak[0][nf]);
      ak[1][nf] = MFMA16(a1, bw2, ak[1][nf]);
    }
#pragma unroll
    for (int mi = 0; mi < 4; mi++) {
      bf8 aw = *(const bf8*)&wv[(size_t)((mi << 4) + lc) * 512 + ko];
      av[mi][0] = MFMA16(aw, a0, av[mi][0]);
      av[mi][1] = MFMA16(aw, a1, av[mi][1]);
    }
  }
#pragma unroll
  for (int mi = 0; mi < 2; mi++)
#pragma unroll
    for (int nf = 0; nf < 4; nf++)
#pragma unroll
      for (int r = 0; r < 4; r++) {
        int b = (wid << 5) + (mi << 4) + cr + r;
        int d = (nf << 4) + lc;
        qs[b][d] = f2bf(aq[mi][nf][r] + bqv[nf]);
        ksm[b][d] = f2bf(ak[mi][nf][r] + bkv[nf]);
      }
#pragma unroll
  for (int mi = 0; mi < 4; mi++)
#pragma unroll
    for (int c2 = 0; c2 < 2; c2++)
#pragma unroll
      for (int r = 0; r < 4; r++) {
        int d = (mi << 4) + cr + r;
        int c = (wid << 5) + (c2 << 4) + lc;
        vt[d][c] = f2bf(av[mi][c2][r] + bvv[mi][r]);
      }
  __syncthreads();

  f32x4 as_[2][8] = {};
#pragma unroll
  for (int ks = 0; ks < 2; ks++) {
    int ko = (ks << 5) + (lq << 3);
    bf8 a0 = *(const bf8*)&qs[(wid << 5) + lc][ko];
    bf8 a1 = *(const bf8*)&qs[(wid << 5) + 16 + lc][ko];
#pragma unroll
    for (int nf = 0; nf < 8; nf++) {
      bf8 bw = *(const bf8*)&ksm[(nf << 4) + lc][ko];
      as_[0][nf] = MFMA16(a0, bw, as_[0][nf]);
      as_[1][nf] = MFMA16(a1, bw, as_[1][nf]);
    }
  }
#pragma unroll
  for (int mi = 0; mi < 2; mi++)
#pragma unroll
    for (int nf = 0; nf < 8; nf++)
#pragma unroll
      for (int r = 0; r < 4; r++)
        sc[(wid << 5) + (mi << 4) + cr + r][(nf << 4) + lc] = as_[mi][nf][r] * 0.125f;
  __syncthreads();

  {
    int row = tid & 127, half = tid >> 7;
    int cb = half << 6;
    float mx = -1e30f;
    for (int j = 0; j < 64; j++) mx = fmaxf(mx, sc[row][cb + j]);
    pmax[(half << 7) + row] = mx;
    __syncthreads();
    mx = fmaxf(pmax[row], pmax[128 + row]);
    float s = 0.f;
    for (int j = 0; j < 64; j++) { float ev = __expf(sc[row][cb + j] - mx); s += ev; sc[row][cb + j] = ev; }
    psum[(half << 7) + row] = s;
    __syncthreads();
    float inv = 1.f / (psum[row] + psum[128 + row]);
    for (int j = 0; j < 64; j++) ps[row][cb + j] = f2bf(sc[row][cb + j] * inv);
  }
  __syncthreads();

  f32x4 ao[2][4] = {};
#pragma unroll
  for (int ks = 0; ks < 4; ks++) {
    int ko = (ks << 5) + (lq << 3);
    bf8 a0 = *(const bf8*)&ps[(wid << 5) + lc][ko];
    bf8 a1 = *(const bf8*)&ps[(wid << 5) + 16 + lc][ko];
#pragma unroll
    for (int nf = 0; nf < 4; nf++) {
      bf8 bw = *(const bf8*)&vt[(nf << 4) + lc][ko];
      ao[0][nf] = MFMA16(a0, bw, ao[0][nf]);
      ao[1][nf] = MFMA16(a1, bw, ao[1][nf]);
    }
  }
  float pm[4];
#pragma unroll
  for (int nf = 0; nf < 4; nf++) {
    float s = 0.f;
#pragma unroll
    for (int mi = 0; mi < 2; mi++)
#pragma unroll
      for (int r = 0; r < 4; r++) s += ao[mi][nf][r];
    s += __shfl_xor(s, 16, 64);
    s += __shfl_xor(s, 32, 64);
    pm[nf] = s;
  }
  if (lq == 0) {
#pragma unroll
    for (int nf = 0; nf < 4; nf++) red[(wid << 6) + (nf << 4) + lc] = pm[nf];
  }
  __syncthreads();
  if (tid < 64) {
    float s = red[tid] + red[64 + tid] + red[128 + tid] + red[192 + tid];
    attmean[(t << 9) + (n << 6) + tid] = s * 0.0078125f;
  }
}

// ------------- attmean @ Wo + bo -------------
__global__ __launch_bounds__(256) void k_olm(const float* __restrict__ am, const float* __restrict__ Wo,
                                             const float* __restrict__ bo, float* __restrict__ olm) {
  __shared__ float row[512];
  int t = blockIdx.x >> 1, h0 = (blockIdx.x & 1) << 8;
  int tid = threadIdx.x;
  row[tid] = am[(t << 9) + tid];
  row[tid + 256] = am[(t << 9) + 256 + tid];
  __syncthreads();
  int h = h0 + tid;
  float s = bo[h];
  for (int k = 0; k < 512; k++) s += row[k] * Wo[(k << 9) + h];
  olm[(t << 9) + h] = s;
}

// ------------- final MLP + softmax -------------
__global__ __launch_bounds__(64) void k_final(const float* __restrict__ olmp, const float* __restrict__ hrm,
                                              const float* __restrict__ Wh, const float* __restrict__ bh,
                                              const float* __restrict__ Wa, const float* __restrict__ ba,
                                              float* __restrict__ out) {
  __shared__ float cat[1024];
  int t = blockIdx.x, j = threadIdx.x;
  for (int i = j; i < 512; i += 64) {
    cat[i] = olmp[(t << 9) + i];
    cat[512 + i] = hrm[(t << 9) + i];
  }
  __syncthreads();
  float f = bh[j];
  for (int k = 0; k < 1024; k++) f += cat[k] * Wh[(k << 6) + j];
  float p0 = f * Wa[j * 2], p1 = f * Wa[j * 2 + 1];
#pragma unroll
  for (int o = 32; o > 0; o >>= 1) { p0 += __shfl_down(p0, o); p1 += __shfl_down(p1, o); }
  if (j == 0) {
    p0 += ba[0]; p1 += ba[1];
    float m = fmaxf(p0, p1);
    float e0 = __expf(p0 - m), e1 = __expf(p1 - m);
    float inv = 1.f / (e0 + e1);
    out[t * 2] = e0 * inv;
    out[t * 2 + 1] = e1 * inv;
  }
}

extern "C" void kernel_launch(void* const* d_in, const int* in_sizes, int n_in,
                              void* d_out, int out_size, void* d_ws, size_t ws_size,
                              hipStream_t stream) {
  const int*   seq_l = (const int*)d_in[0];
  const int*   seq_r = (const int*)d_in[1];
  const float* emb_l = (const float*)d_in[2];
  const float* emb_r = (const float*)d_in[3];
  const float* Wih_l = (const float*)d_in[4];
  const float* Whh_l = (const float*)d_in[5];
  const float* bih_l = (const float*)d_in[6];
  const float* bhh_l = (const float*)d_in[7];
  const float* Wih_r = (const float*)d_in[8];
  const float* Whh_r = (const float*)d_in[9];
  const float* bih_r = (const float*)d_in[10];
  const float* bhh_r = (const float*)d_in[11];
  const float* Wq = (const float*)d_in[12];
  const float* bq = (const float*)d_in[13];
  const float* Wk = (const float*)d_in[14];
  const float* bk = (const float*)d_in[15];
  const float* Wv = (const float*)d_in[16];
  const float* bv = (const float*)d_in[17];
  const float* Wo = (const float*)d_in[18];
  const float* bo = (const float*)d_in[19];
  const float* Wh = (const float*)d_in[20];
  const float* bhc = (const float*)d_in[21];
  const float* Wa = (const float*)d_in[22];
  const float* ba = (const float*)d_in[23];
  float* out = (float*)d_out;

  char* ws = (char*)d_ws;
  size_t off = 0;
  auto alloc = [&](size_t bytes) { char* p = ws + off; off += (bytes + 255) & ~(size_t)255; return p; };
  u16*   hsl  = (u16*)alloc(33554432);
  u16*   hsr  = (u16*)alloc(33554432);
  u16*   Whl  = (u16*)alloc(2097152);
  u16*   Whr  = (u16*)alloc(2097152);
  u16*   WqT  = (u16*)alloc(524288);
  u16*   WkT  = (u16*)alloc(524288);
  u16*   WvT  = (u16*)alloc(524288);
  float* bsl  = (float*)alloc(8192);
  float* bsr  = (float*)alloc(8192);
  unsigned* hx = (unsigned*)alloc(524288);   // 4 regions x 32768 u32
  float* cst  = (float*)alloc(524288);
  unsigned* flg = (unsigned*)alloc(2048);    // 8 pods x 64 u32
  float* am   = (float*)alloc(524288);
  float* hrm  = (float*)alloc(524288);
  float* olm  = (float*)alloc(524288);
  size_t fixed = off;

  int Tc = 0;
  const int cands[3] = {128, 64, 32};
  for (int i = 0; i < 3; i++) {
    size_t need = fixed + 4ull * (size_t)cands[i] * 524288ull;  // 2 enc x dbuf
    if (need <= ws_size) { Tc = cands[i]; break; }
  }
  if (Tc == 0) {
    k_fill<<<2, 256, 0, stream>>>(out, out_size, 0.25f);
    return;
  }
  size_t gbytes = (size_t)Tc * 524288ull;
  u16* Glb[2]; u16* Grb[2];
  Glb[0] = (u16*)alloc(gbytes); Glb[1] = (u16*)alloc(gbytes);
  Grb[0] = (u16*)alloc(gbytes); Grb[1] = (u16*)alloc(gbytes);

  // merged prep + chunk-0 gemms
  k_prep<<<5138 + (Tc << 5), 256, 0, stream>>>(
      flg, Whh_l, Whl, Whh_r, Whr, Wq, WqT, Wk, WkT, Wv, WvT,
      bih_l, bhh_l, bsl, bih_r, bhh_r, bsr,
      seq_l, seq_r, emb_l, emb_r, Wih_l, Wih_r, Glb[0], Grb[0], Tc);

  int nC = 256 / Tc;
  for (int c = 0; c < nC; c++) {
    int hg = (c + 1 < nC);
    int grid = 128 + (hg ? (Tc << 5) : 0);
    k_fused<<<grid, 256, 0, stream>>>(
        Glb[c & 1], Grb[c & 1], Glb[(c + 1) & 1], Grb[(c + 1) & 1],
        seq_l, seq_r, emb_l, emb_r, Wih_l, Wih_r,
        Whl, Whr, bsl, bsr, hsl, hsr, hx, cst, flg,
        c * Tc, Tc, (c + 1) * Tc * 128, Tc);
  }
  k_meanr<<<256, 256, 0, stream>>>(hsr, hrm);
  k_attn<<<2048, 256, 0, stream>>>(hsl, WqT, WkT, WvT, bq, bk, bv, am);
  k_olm<<<512, 256, 0, stream>>>(am, Wo, bo, olm);
  k_final<<<256, 64, 0, stream>>>(olm, hrm, Wh, bhc, Wa, ba, out);
}